// Round 1
// baseline (761.279 us; speedup 1.0000x reference)
//
#include <hip/hip_runtime.h>
#include <hip/hip_bf16.h>
#include <math.h>

#define T_TOK 8192
#define E_NUM 8

typedef __attribute__((ext_vector_type(8))) short short8;
typedef __attribute__((ext_vector_type(4))) float floatx4;

__device__ __forceinline__ unsigned short f2bf(float f) {
  unsigned int u = __builtin_bit_cast(unsigned int, f);
  u += 0x7fffu + ((u >> 16) & 1u);
  return (unsigned short)(u >> 16);
}

// ---------------- Router: fp64 accumulation for exact top-2 ----------------
// 8 tokens per block, 128 threads (one per hidden unit of the router MLP).
__global__ __launch_bounds__(128) void router_kernel(
    const float* __restrict__ x, const float* __restrict__ rw1,
    const float* __restrict__ rw2, int* __restrict__ cnt,
    int* __restrict__ tid_list, float* __restrict__ tw_list) {
  __shared__ float xs[8][1024];     // 32 KB
  __shared__ double hs[8][128];     // 8 KB
  __shared__ double ls[8][8];
  const int t = threadIdx.x;
  const int tok0 = blockIdx.x * 8;

  // load 8 token rows (fp32, exact)
  const float4* xsrc = (const float4*)(x + (size_t)tok0 * 1024);
  float4* xd = (float4*)&xs[0][0];
  for (int i = 0; i < 16; ++i) xd[t + i * 128] = xsrc[t + i * 128];
  __syncthreads();

  double acc[8];
#pragma unroll
  for (int tt = 0; tt < 8; ++tt) acc[tt] = 0.0;
  for (int d = 0; d < 1024; ++d) {
    double w = (double)rw1[d * 128 + t];
#pragma unroll
    for (int tt = 0; tt < 8; ++tt) acc[tt] = fma((double)xs[tt][d], w, acc[tt]);
  }
#pragma unroll
  for (int tt = 0; tt < 8; ++tt) {
    double a = acc[tt];
    hs[tt][t] = a / (1.0 + exp(-a));  // silu
  }
  __syncthreads();
  if (t < 64) {
    int tt = t >> 3, e = t & 7;
    double l = 0.0;
    for (int j = 0; j < 128; ++j) l = fma(hs[tt][j], (double)rw2[j * 8 + e], l);
    ls[tt][e] = l;
  }
  __syncthreads();
  if (t < 8) {
    int tt = t;
    double l[8];
#pragma unroll
    for (int e = 0; e < 8; ++e) l[e] = ls[tt][e];
    int i0 = 0;
#pragma unroll
    for (int e = 1; e < 8; ++e) if (l[e] > l[i0]) i0 = e;  // strict >: lower idx wins ties
    int i1 = (i0 == 0) ? 1 : 0;
#pragma unroll
    for (int e = 0; e < 8; ++e) if (e != i0 && l[e] > l[i1]) i1 = e;
    double p1 = exp(l[i1] - l[i0]);       // p0 = 1
    double s = 1.0 + p1;
    float w0 = (float)(1.0 / s), w1 = (float)(p1 / s);
    int tok = tok0 + tt;
    int pos0 = atomicAdd(&cnt[i0], 1);
    tid_list[i0 * T_TOK + pos0] = tok; tw_list[i0 * T_TOK + pos0] = w0;
    int pos1 = atomicAdd(&cnt[i1], 1);
    tid_list[i1 * T_TOK + pos1] = tok; tw_list[i1 * T_TOK + pos1] = w1;
  }
}

__global__ void prefix_kernel(const int* __restrict__ cnt, int* __restrict__ base) {
  if (threadIdx.x == 0 && blockIdx.x == 0) {
    int s = 0;
    for (int e = 0; e < E_NUM; ++e) { base[e] = s; s += cnt[e]; }
  }
}

// ---------------- fp32 -> bf16 elementwise ----------------
__global__ __launch_bounds__(256) void convert_x_kernel(const float* __restrict__ in,
                                                        unsigned short* __restrict__ out) {
  size_t i = ((size_t)blockIdx.x * 256 + threadIdx.x) * 4;
  float4 v = *(const float4*)(in + i);
  ushort4 o;
  o.x = f2bf(v.x); o.y = f2bf(v.y); o.z = f2bf(v.z); o.w = f2bf(v.w);
  *(ushort4*)(out + i) = o;
}

// ---------------- tiled transpose + convert: in [e][R][C] fp32 -> out [e][C][R] bf16 ----
__global__ __launch_bounds__(256) void transpose_bf16_kernel(
    const float* __restrict__ in, unsigned short* __restrict__ out, int R, int C) {
  __shared__ unsigned short tile[64][65];
  const int e = blockIdx.z;
  const int r0 = blockIdx.y * 64, c0 = blockIdx.x * 64;
  const float* src = in + (size_t)e * R * C;
  unsigned short* dst = out + (size_t)e * R * C;
  const int t = threadIdx.x;
  const int cc = (t & 15) * 4;
#pragma unroll
  for (int p = 0; p < 4; ++p) {
    int r = p * 16 + (t >> 4);
    float4 v = *(const float4*)(src + (size_t)(r0 + r) * C + c0 + cc);
    tile[cc + 0][r] = f2bf(v.x);
    tile[cc + 1][r] = f2bf(v.y);
    tile[cc + 2][r] = f2bf(v.z);
    tile[cc + 3][r] = f2bf(v.w);
  }
  __syncthreads();
#pragma unroll
  for (int p = 0; p < 4; ++p) {
    int fr = p * 16 + (t >> 4);
    ushort4 o;
    o.x = tile[fr][cc + 0]; o.y = tile[fr][cc + 1];
    o.z = tile[fr][cc + 2]; o.w = tile[fr][cc + 3];
    *(ushort4*)(dst + (size_t)(c0 + fr) * R + r0 + cc) = o;
  }
}

// ---------------- GEMM1: h[slot][f] = silu( x[tok][:] @ W1[e][:][f] ), bf16 MFMA ----
__global__ __launch_bounds__(256) void gemm1_kernel(
    const unsigned short* __restrict__ xb,   // [T][1024] bf16
    const unsigned short* __restrict__ w1t,  // [E][2048][1024] bf16 (f-major)
    const int* __restrict__ cnt, const int* __restrict__ base,
    const int* __restrict__ tid_list,
    unsigned short* __restrict__ h_buf) {    // [2T][2048] bf16
  const int e = blockIdx.z;
  const int m0 = blockIdx.y * 128;
  const int n0 = blockIdx.x * 128;
  const int count = cnt[e];
  if (m0 >= count) return;
  const int bs = base[e];

  __shared__ __align__(16) unsigned short As[128][40];
  __shared__ __align__(16) unsigned short Bs[128][40];

  const int t = threadIdx.x;
  const int wave = t >> 6, lane = t & 63;
  const int quad = lane >> 4, lr = lane & 15;
  const int wm = (wave & 1) * 64, wn = (wave >> 1) * 64;

  floatx4 zero = {0.f, 0.f, 0.f, 0.f};
  floatx4 acc[4][4];
#pragma unroll
  for (int i = 0; i < 4; ++i)
#pragma unroll
    for (int j = 0; j < 4; ++j) acc[i][j] = zero;

  const int sr = t >> 1;   // staging row 0..127
  const int sh = t & 1;    // 32B half of the 64B row-chunk
  int arow = m0 + sr;
  int tok = tid_list[e * T_TOK + (arow < count ? arow : m0)];
  const uint4* asrc = (const uint4*)(xb + (size_t)tok * 1024);
  const uint4* bsrc = (const uint4*)(w1t + ((size_t)e * 2048 + n0 + sr) * 1024);

  for (int k0 = 0; k0 < 1024; k0 += 32) {
    int eo = (k0 + sh * 16) >> 3;  // uint4 index (8 bf16 per uint4)
    uint4 a0 = asrc[eo], a1 = asrc[eo + 1];
    uint4 b0 = bsrc[eo], b1 = bsrc[eo + 1];
    *(uint4*)&As[sr][sh * 16] = a0;
    *(uint4*)&As[sr][sh * 16 + 8] = a1;
    *(uint4*)&Bs[sr][sh * 16] = b0;
    *(uint4*)&Bs[sr][sh * 16 + 8] = b1;
    __syncthreads();
    short8 af[4], bfr[4];
#pragma unroll
    for (int i = 0; i < 4; ++i) af[i] = *(const short8*)&As[wm + i * 16 + lr][quad * 8];
#pragma unroll
    for (int j = 0; j < 4; ++j) bfr[j] = *(const short8*)&Bs[wn + j * 16 + lr][quad * 8];
#pragma unroll
    for (int i = 0; i < 4; ++i)
#pragma unroll
      for (int j = 0; j < 4; ++j)
        acc[i][j] = __builtin_amdgcn_mfma_f32_16x16x32_bf16(af[i], bfr[j], acc[i][j], 0, 0, 0);
    __syncthreads();
  }

#pragma unroll
  for (int i = 0; i < 4; ++i) {
#pragma unroll
    for (int r = 0; r < 4; ++r) {
      int grow = m0 + wm + i * 16 + quad * 4 + r;
      if (grow < count) {
        size_t rowoff = (size_t)(bs + grow) * 2048;
#pragma unroll
        for (int j = 0; j < 4; ++j) {
          float v = acc[i][j][r];
          float s = v / (1.0f + __expf(-v));
          h_buf[rowoff + n0 + wn + j * 16 + lr] = f2bf(s);
        }
      }
    }
  }
}

// ---------------- GEMM2: out[tok][:] += w * ( h[slot][:] @ W2[e][:][:] ) ----
__global__ __launch_bounds__(256) void gemm2_kernel(
    const unsigned short* __restrict__ h_buf,  // [2T][2048] bf16
    const unsigned short* __restrict__ w2t,    // [E][1024][2048] bf16 (d-major)
    const int* __restrict__ cnt, const int* __restrict__ base,
    const int* __restrict__ tid_list, const float* __restrict__ tw_list,
    float* __restrict__ out) {                 // [T][1024] fp32
  const int e = blockIdx.z;
  const int m0 = blockIdx.y * 128;
  const int n0 = blockIdx.x * 128;
  const int count = cnt[e];
  if (m0 >= count) return;
  const int bs = base[e];

  __shared__ __align__(16) unsigned short As[128][40];
  __shared__ __align__(16) unsigned short Bs[128][40];

  const int t = threadIdx.x;
  const int wave = t >> 6, lane = t & 63;
  const int quad = lane >> 4, lr = lane & 15;
  const int wm = (wave & 1) * 64, wn = (wave >> 1) * 64;

  floatx4 zero = {0.f, 0.f, 0.f, 0.f};
  floatx4 acc[4][4];
#pragma unroll
  for (int i = 0; i < 4; ++i)
#pragma unroll
    for (int j = 0; j < 4; ++j) acc[i][j] = zero;

  const int sr = t >> 1;
  const int sh = t & 1;
  int arow = m0 + sr;
  int slot = bs + (arow < count ? arow : 0);
  const uint4* asrc = (const uint4*)(h_buf + (size_t)slot * 2048);
  const uint4* bsrc = (const uint4*)(w2t + ((size_t)e * 1024 + n0 + sr) * 2048);

  for (int k0 = 0; k0 < 2048; k0 += 32) {
    int eo = (k0 + sh * 16) >> 3;
    uint4 a0 = asrc[eo], a1 = asrc[eo + 1];
    uint4 b0 = bsrc[eo], b1 = bsrc[eo + 1];
    *(uint4*)&As[sr][sh * 16] = a0;
    *(uint4*)&As[sr][sh * 16 + 8] = a1;
    *(uint4*)&Bs[sr][sh * 16] = b0;
    *(uint4*)&Bs[sr][sh * 16 + 8] = b1;
    __syncthreads();
    short8 af[4], bfr[4];
#pragma unroll
    for (int i = 0; i < 4; ++i) af[i] = *(const short8*)&As[wm + i * 16 + lr][quad * 8];
#pragma unroll
    for (int j = 0; j < 4; ++j) bfr[j] = *(const short8*)&Bs[wn + j * 16 + lr][quad * 8];
#pragma unroll
    for (int i = 0; i < 4; ++i)
#pragma unroll
      for (int j = 0; j < 4; ++j)
        acc[i][j] = __builtin_amdgcn_mfma_f32_16x16x32_bf16(af[i], bfr[j], acc[i][j], 0, 0, 0);
    __syncthreads();
  }

#pragma unroll
  for (int i = 0; i < 4; ++i) {
#pragma unroll
    for (int r = 0; r < 4; ++r) {
      int grow = m0 + wm + i * 16 + quad * 4 + r;
      if (grow < count) {
        int tok = tid_list[e * T_TOK + grow];
        float w = tw_list[e * T_TOK + grow];
        size_t rowoff = (size_t)tok * 1024;
#pragma unroll
        for (int j = 0; j < 4; ++j) {
          unsafeAtomicAdd(&out[rowoff + n0 + wn + j * 16 + lr], acc[i][j][r] * w);
        }
      }
    }
  }
}

extern "C" void kernel_launch(void* const* d_in, const int* in_sizes, int n_in,
                              void* d_out, int out_size, void* d_ws, size_t ws_size,
                              hipStream_t stream) {
  const float* x   = (const float*)d_in[0];
  const float* rw1 = (const float*)d_in[1];
  const float* rw2 = (const float*)d_in[2];
  const float* W1  = (const float*)d_in[3];
  const float* W2  = (const float*)d_in[4];
  float* out = (float*)d_out;

  char* ws = (char*)d_ws;
  // workspace layout (256B-ish aligned): ~145 MB total
  int*            cnt      = (int*)(ws + 0);               // 32 B
  int*            base     = (int*)(ws + 64);              // 32 B
  int*            tid_list = (int*)(ws + 512);             // 256 KB
  float*          tw_list  = (float*)(ws + 512 + 262144);  // 256 KB
  unsigned short* xb       = (unsigned short*)(ws + 524800);    // 16 MB
  unsigned short* w1t      = (unsigned short*)(ws + 17302016);  // 32 MB
  unsigned short* w2t      = (unsigned short*)(ws + 50856448);  // 32 MB
  unsigned short* hbuf     = (unsigned short*)(ws + 84410880);  // 64 MB

  hipMemsetAsync(d_out, 0, (size_t)T_TOK * 1024 * 4, stream);
  hipMemsetAsync(cnt, 0, 64, stream);

  hipLaunchKernelGGL(router_kernel, dim3(1024), dim3(128), 0, stream,
                     x, rw1, rw2, cnt, tid_list, tw_list);
  hipLaunchKernelGGL(prefix_kernel, dim3(1), dim3(1), 0, stream, cnt, base);
  hipLaunchKernelGGL(convert_x_kernel, dim3(8192), dim3(256), 0, stream, x, xb);
  hipLaunchKernelGGL(transpose_bf16_kernel, dim3(32, 16, 8), dim3(256), 0, stream,
                     W1, w1t, 1024, 2048);
  hipLaunchKernelGGL(transpose_bf16_kernel, dim3(16, 32, 8), dim3(256), 0, stream,
                     W2, w2t, 2048, 1024);
  hipLaunchKernelGGL(gemm1_kernel, dim3(16, 64, 8), dim3(256), 0, stream,
                     xb, w1t, cnt, base, tid_list, hbuf);
  hipLaunchKernelGGL(gemm2_kernel, dim3(8, 64, 8), dim3(256), 0, stream,
                     hbuf, w2t, cnt, base, tid_list, tw_list, out);
}

// Round 2
// 565.505 us; speedup vs baseline: 1.3462x; 1.3462x over previous
//
#include <hip/hip_runtime.h>
#include <hip/hip_bf16.h>
#include <math.h>

#define T_TOK 8192
#define E_NUM 8
#define GAP_TAU 2e-3f

typedef __attribute__((ext_vector_type(8))) short short8;
typedef __attribute__((ext_vector_type(4))) float floatx4;

__device__ __forceinline__ unsigned short f2bf(float f) {
  unsigned int u = __builtin_bit_cast(unsigned int, f);
  u += 0x7fffu + ((u >> 16) & 1u);
  return (unsigned short)(u >> 16);
}

// async global->LDS, 16B per lane; LDS dest = wave-uniform base + lane*16
__device__ __forceinline__ void async16(const unsigned short* g, unsigned short* l) {
  __builtin_amdgcn_global_load_lds(
      (const __attribute__((address_space(1))) void*)g,
      (__attribute__((address_space(3))) void*)l, 16, 0, 0);
}

// ---------------- Router pass 1: fp32 logits, top-2, flag small-gap tokens ----
// 8 tokens/block, 256 threads: j = t&127 (hidden unit), h = t>>7 (d-half).
__global__ __launch_bounds__(256) void router_fp32_kernel(
    const float* __restrict__ x, const float* __restrict__ rw1,
    const float* __restrict__ rw2,
    int* __restrict__ tok_top, float* __restrict__ tok_w,
    int* __restrict__ fix_list, int* __restrict__ fix_cnt) {
  __shared__ __align__(16) float xs[8][1024];  // 32 KB
  __shared__ float ph[128][8];                 // 4 KB, h=1 partials
  __shared__ float hs[8][129];                 // padded: bank-conflict-free col reads
  __shared__ float ls[8][8];
  const int t = threadIdx.x;
  const int tok0 = blockIdx.x * 8;

  // stage 8 token rows fp32 (exact)
  {
    const float4* xsrc = (const float4*)(x + (size_t)tok0 * 1024);
    float4* xd = (float4*)&xs[0][0];
#pragma unroll
    for (int i = 0; i < 8; ++i) xd[t + i * 256] = xsrc[t + i * 256];
  }
  __syncthreads();

  const int j = t & 127, h = t >> 7;
  float acc[8];
#pragma unroll
  for (int tt = 0; tt < 8; ++tt) acc[tt] = 0.f;

  const int dbeg = h * 512, dend = dbeg + 512;
#pragma unroll 2
  for (int d0 = dbeg; d0 < dend; d0 += 4) {
    float w0 = rw1[(d0 + 0) * 128 + j];
    float w1 = rw1[(d0 + 1) * 128 + j];
    float w2 = rw1[(d0 + 2) * 128 + j];
    float w3 = rw1[(d0 + 3) * 128 + j];
    float4 xv[8];
#pragma unroll
    for (int tt = 0; tt < 8; ++tt) xv[tt] = *(const float4*)&xs[tt][d0];
#pragma unroll
    for (int tt = 0; tt < 8; ++tt) {
      acc[tt] = fmaf(xv[tt].x, w0, acc[tt]);
      acc[tt] = fmaf(xv[tt].y, w1, acc[tt]);
      acc[tt] = fmaf(xv[tt].z, w2, acc[tt]);
      acc[tt] = fmaf(xv[tt].w, w3, acc[tt]);
    }
  }
  if (h == 1) {
#pragma unroll
    for (int tt = 0; tt < 8; ++tt) ph[j][tt] = acc[tt];
  }
  __syncthreads();
  if (h == 0) {
#pragma unroll
    for (int tt = 0; tt < 8; ++tt) {
      float a = acc[tt] + ph[j][tt];
      hs[tt][j] = a / (1.f + expf(-a));
    }
  }
  __syncthreads();
  if (t < 64) {
    int tt = t >> 3, e = t & 7;
    float l = 0.f;
#pragma unroll 4
    for (int jj = 0; jj < 128; ++jj) l = fmaf(hs[tt][jj], rw2[jj * 8 + e], l);
    ls[tt][e] = l;
  }
  __syncthreads();
  if (t < 8) {
    int tt = t;
    float l[8];
#pragma unroll
    for (int e = 0; e < 8; ++e) l[e] = ls[tt][e];
    int i0 = 0;
#pragma unroll
    for (int e = 1; e < 8; ++e) if (l[e] > l[i0]) i0 = e;
    int i1 = (i0 == 0) ? 1 : 0;
#pragma unroll
    for (int e = 0; e < 8; ++e) if (e != i0 && l[e] > l[i1]) i1 = e;
    float v2 = -3.4e38f;
#pragma unroll
    for (int e = 0; e < 8; ++e) if (e != i0 && e != i1 && l[e] > v2) v2 = l[e];
    float gap = l[i1] - v2;           // 2nd-vs-3rd: only this flips the top-2 SET
    float p = expf(l[i1] - l[i0]);
    float w0 = 1.f / (1.f + p);
    int tok = tok0 + tt;
    tok_top[2 * tok] = i0; tok_top[2 * tok + 1] = i1;
    tok_w[2 * tok] = w0;   tok_w[2 * tok + 1] = 1.f - w0;
    if (gap < GAP_TAU) { int pos = atomicAdd(fix_cnt, 1); fix_list[pos] = tok; }
  }
}

// ---------------- Router pass 2: exact fp64 recompute for flagged tokens ----
__global__ __launch_bounds__(256) void router_fix_kernel(
    const float* __restrict__ x, const float* __restrict__ rw1,
    const float* __restrict__ rw2, const int* __restrict__ fix_list,
    const int* __restrict__ fix_cnt,
    int* __restrict__ tok_top, float* __restrict__ tok_w) {
  __shared__ __align__(16) float xs[1024];
  __shared__ double red[128];
  __shared__ double hs[128];
  __shared__ double ls[8];
  const int t = threadIdx.x;
  const int nfix = *fix_cnt;
  for (int it = blockIdx.x; it < nfix; it += gridDim.x) {
    int tok = fix_list[it];
    ((float4*)xs)[t] = ((const float4*)(x + (size_t)tok * 1024))[t];
    __syncthreads();
    const int j = t & 127, h = t >> 7;
    double a0 = 0, a1 = 0, a2 = 0, a3 = 0;
    const int dbeg = h * 512;
    for (int d0 = dbeg; d0 < dbeg + 512; d0 += 4) {
      a0 = fma((double)xs[d0 + 0], (double)rw1[(d0 + 0) * 128 + j], a0);
      a1 = fma((double)xs[d0 + 1], (double)rw1[(d0 + 1) * 128 + j], a1);
      a2 = fma((double)xs[d0 + 2], (double)rw1[(d0 + 2) * 128 + j], a2);
      a3 = fma((double)xs[d0 + 3], (double)rw1[(d0 + 3) * 128 + j], a3);
    }
    double a = (a0 + a1) + (a2 + a3);
    if (h == 1) red[j] = a;
    __syncthreads();
    if (h == 0) {
      double s = a + red[j];
      hs[j] = s / (1.0 + exp(-s));
    }
    __syncthreads();
    if (t < 8) {
      int e = t;
      double l = 0;
      for (int jj = 0; jj < 128; ++jj) l = fma(hs[jj], (double)rw2[jj * 8 + e], l);
      ls[e] = l;
    }
    __syncthreads();
    if (t == 0) {
      double l[8];
#pragma unroll
      for (int e = 0; e < 8; ++e) l[e] = ls[e];
      int i0 = 0;
#pragma unroll
      for (int e = 1; e < 8; ++e) if (l[e] > l[i0]) i0 = e;
      int i1 = (i0 == 0) ? 1 : 0;
#pragma unroll
      for (int e = 0; e < 8; ++e) if (e != i0 && l[e] > l[i1]) i1 = e;
      double p = exp(l[i1] - l[i0]);
      double w0 = 1.0 / (1.0 + p);
      tok_top[2 * tok] = i0; tok_top[2 * tok + 1] = i1;
      tok_w[2 * tok] = (float)w0; tok_w[2 * tok + 1] = (float)(1.0 - w0);
    }
    __syncthreads();
  }
}

// ---------------- Scatter: build per-expert token lists (block-aggregated) ----
__global__ __launch_bounds__(256) void scatter_kernel(
    const int* __restrict__ tok_top, const float* __restrict__ tok_w,
    int* __restrict__ cnt, int* __restrict__ tid_list, float* __restrict__ tw_list) {
  __shared__ int hist[8], run[8];
  const int t = threadIdx.x;
  if (t < 8) hist[t] = 0;
  __syncthreads();
  const int tok = blockIdx.x * 256 + t;
  const int e0 = tok_top[2 * tok], e1 = tok_top[2 * tok + 1];
  atomicAdd(&hist[e0], 1);
  atomicAdd(&hist[e1], 1);
  __syncthreads();
  if (t < 8) run[t] = atomicAdd(&cnt[t], hist[t]);
  __syncthreads();
  int p0 = atomicAdd(&run[e0], 1);
  tid_list[e0 * T_TOK + p0] = tok; tw_list[e0 * T_TOK + p0] = tok_w[2 * tok];
  int p1 = atomicAdd(&run[e1], 1);
  tid_list[e1 * T_TOK + p1] = tok; tw_list[e1 * T_TOK + p1] = tok_w[2 * tok + 1];
}

__global__ void prefix_kernel(const int* __restrict__ cnt, int* __restrict__ base) {
  if (threadIdx.x == 0 && blockIdx.x == 0) {
    int s = 0;
    for (int e = 0; e < E_NUM; ++e) { base[e] = s; s += cnt[e]; }
  }
}

// ---------------- fp32 -> bf16 elementwise ----------------
__global__ __launch_bounds__(256) void convert_x_kernel(const float* __restrict__ in,
                                                        unsigned short* __restrict__ out) {
  size_t i = ((size_t)blockIdx.x * 256 + threadIdx.x) * 4;
  float4 v = *(const float4*)(in + i);
  ushort4 o;
  o.x = f2bf(v.x); o.y = f2bf(v.y); o.z = f2bf(v.z); o.w = f2bf(v.w);
  *(ushort4*)(out + i) = o;
}

// ---------------- tiled transpose + convert: [e][R][C] fp32 -> [e][C][R] bf16 ----
__global__ __launch_bounds__(256) void transpose_bf16_kernel(
    const float* __restrict__ in, unsigned short* __restrict__ out, int R, int C) {
  __shared__ unsigned short tile[64][65];
  const int e = blockIdx.z;
  const int r0 = blockIdx.y * 64, c0 = blockIdx.x * 64;
  const float* src = in + (size_t)e * R * C;
  unsigned short* dst = out + (size_t)e * R * C;
  const int t = threadIdx.x;
  const int cc = (t & 15) * 4;
#pragma unroll
  for (int p = 0; p < 4; ++p) {
    int r = p * 16 + (t >> 4);
    float4 v = *(const float4*)(src + (size_t)(r0 + r) * C + c0 + cc);
    tile[cc + 0][r] = f2bf(v.x);
    tile[cc + 1][r] = f2bf(v.y);
    tile[cc + 2][r] = f2bf(v.z);
    tile[cc + 3][r] = f2bf(v.w);
  }
  __syncthreads();
#pragma unroll
  for (int p = 0; p < 4; ++p) {
    int fr = p * 16 + (t >> 4);
    ushort4 o;
    o.x = tile[fr][cc + 0]; o.y = tile[fr][cc + 1];
    o.z = tile[fr][cc + 2]; o.w = tile[fr][cc + 3];
    *(ushort4*)(dst + (size_t)(c0 + fr) * R + r0 + cc) = o;
  }
}

// ============ GEMM1: h[slot][f] = silu( x[tok][:] @ W1t[e][f][:] ) =============
// 128x128 tile, BK=64, global_load_lds(16B) staging, XOR-swizzled LDS chunks:
// physical 16B chunk = logical_chunk ^ (row & 7)  -> fragment ds_read_b128 2-way.
__global__ __launch_bounds__(256) void gemm1_kernel(
    const unsigned short* __restrict__ xb,   // [T][1024] bf16
    const unsigned short* __restrict__ w1t,  // [E][2048][1024] bf16
    const int* __restrict__ cnt, const int* __restrict__ base,
    const int* __restrict__ tid_list,
    unsigned short* __restrict__ h_buf) {    // [2T][2048] bf16
  const int e = blockIdx.z;
  const int m0 = blockIdx.y * 128;
  const int n0 = blockIdx.x * 128;
  const int count = cnt[e];
  if (m0 >= count) return;
  const int bs = base[e];

  __shared__ __align__(16) unsigned short As[128 * 64];  // 16 KB, row stride 64 bf16
  __shared__ __align__(16) unsigned short Bs[128 * 64];  // 16 KB

  const int t = threadIdx.x;
  const int wv = t >> 6, lane = t & 63;
  const int quad = lane >> 4, lr = lane & 15;
  const int wm = (wv & 1) * 64, wn = (wv >> 1) * 64;
  const int lr8 = lane >> 3, lc8 = lane & 7;
  const int chunk = lc8 ^ lr8;  // logical 16B chunk this lane fetches

  // staging sources: wave wv stages tile rows [wv*32, wv*32+32), instr q -> +q*8
  const unsigned short* aptr[4];
  const unsigned short* bptr[4];
#pragma unroll
  for (int q = 0; q < 4; ++q) {
    int ar = m0 + wv * 32 + q * 8 + lr8;
    int ai = ar < count ? ar : count - 1;
    int tok = tid_list[e * T_TOK + ai];
    aptr[q] = xb + (size_t)tok * 1024 + chunk * 8;
    int br = n0 + wv * 32 + q * 8 + lr8;
    bptr[q] = w1t + ((size_t)e * 2048 + br) * 1024 + chunk * 8;
  }
  unsigned short* aldsb = &As[wv * 2048];
  unsigned short* bldsb = &Bs[wv * 2048];

  floatx4 zero = {0.f, 0.f, 0.f, 0.f};
  floatx4 acc[4][4];
#pragma unroll
  for (int i = 0; i < 4; ++i)
#pragma unroll
    for (int j = 0; j < 4; ++j) acc[i][j] = zero;

  for (int k0 = 0; k0 < 1024; k0 += 64) {
    __syncthreads();
#pragma unroll
    for (int q = 0; q < 4; ++q) {
      async16(aptr[q] + k0, aldsb + q * 512);
      async16(bptr[q] + k0, bldsb + q * 512);
    }
    __syncthreads();
#pragma unroll
    for (int ks = 0; ks < 2; ++ks) {
      short8 af[4], bfv[4];
#pragma unroll
      for (int i = 0; i < 4; ++i) {
        int r = wm + i * 16 + lr;
        int pc = (ks * 4 + quad) ^ (lr & 7);
        af[i] = *(const short8*)&As[r * 64 + pc * 8];
      }
#pragma unroll
      for (int j = 0; j < 4; ++j) {
        int r = wn + j * 16 + lr;
        int pc = (ks * 4 + quad) ^ (lr & 7);
        bfv[j] = *(const short8*)&Bs[r * 64 + pc * 8];
      }
#pragma unroll
      for (int i = 0; i < 4; ++i)
#pragma unroll
        for (int j = 0; j < 4; ++j)
          acc[i][j] = __builtin_amdgcn_mfma_f32_16x16x32_bf16(af[i], bfv[j], acc[i][j], 0, 0, 0);
    }
  }

#pragma unroll
  for (int i = 0; i < 4; ++i) {
#pragma unroll
    for (int r = 0; r < 4; ++r) {
      int grow = m0 + wm + i * 16 + quad * 4 + r;
      if (grow < count) {
        size_t rowoff = (size_t)(bs + grow) * 2048;
#pragma unroll
        for (int j = 0; j < 4; ++j) {
          float v = acc[i][j][r];
          float s = v / (1.0f + __expf(-v));
          h_buf[rowoff + n0 + wn + j * 16 + lr] = f2bf(s);
        }
      }
    }
  }
}

// ============ GEMM2: out[tok][:] += w * ( h[slot][:] @ W2t[e][d][:] ) ==========
__global__ __launch_bounds__(256) void gemm2_kernel(
    const unsigned short* __restrict__ h_buf,  // [2T][2048] bf16
    const unsigned short* __restrict__ w2t,    // [E][1024][2048] bf16
    const int* __restrict__ cnt, const int* __restrict__ base,
    const int* __restrict__ tid_list, const float* __restrict__ tw_list,
    float* __restrict__ out) {                 // [T][1024] fp32
  const int e = blockIdx.z;
  const int m0 = blockIdx.y * 128;
  const int n0 = blockIdx.x * 128;
  const int count = cnt[e];
  if (m0 >= count) return;
  const int bs = base[e];

  __shared__ __align__(16) unsigned short As[128 * 64];
  __shared__ __align__(16) unsigned short Bs[128 * 64];

  const int t = threadIdx.x;
  const int wv = t >> 6, lane = t & 63;
  const int quad = lane >> 4, lr = lane & 15;
  const int wm = (wv & 1) * 64, wn = (wv >> 1) * 64;
  const int lr8 = lane >> 3, lc8 = lane & 7;
  const int chunk = lc8 ^ lr8;

  const unsigned short* aptr[4];
  const unsigned short* bptr[4];
#pragma unroll
  for (int q = 0; q < 4; ++q) {
    int ar = m0 + wv * 32 + q * 8 + lr8;
    int ai = ar < count ? ar : count - 1;
    aptr[q] = h_buf + (size_t)(bs + ai) * 2048 + chunk * 8;
    int br = n0 + wv * 32 + q * 8 + lr8;
    bptr[q] = w2t + ((size_t)e * 1024 + br) * 2048 + chunk * 8;
  }
  unsigned short* aldsb = &As[wv * 2048];
  unsigned short* bldsb = &Bs[wv * 2048];

  floatx4 zero = {0.f, 0.f, 0.f, 0.f};
  floatx4 acc[4][4];
#pragma unroll
  for (int i = 0; i < 4; ++i)
#pragma unroll
    for (int j = 0; j < 4; ++j) acc[i][j] = zero;

  for (int k0 = 0; k0 < 2048; k0 += 64) {
    __syncthreads();
#pragma unroll
    for (int q = 0; q < 4; ++q) {
      async16(aptr[q] + k0, aldsb + q * 512);
      async16(bptr[q] + k0, bldsb + q * 512);
    }
    __syncthreads();
#pragma unroll
    for (int ks = 0; ks < 2; ++ks) {
      short8 af[4], bfv[4];
#pragma unroll
      for (int i = 0; i < 4; ++i) {
        int r = wm + i * 16 + lr;
        int pc = (ks * 4 + quad) ^ (lr & 7);
        af[i] = *(const short8*)&As[r * 64 + pc * 8];
      }
#pragma unroll
      for (int j = 0; j < 4; ++j) {
        int r = wn + j * 16 + lr;
        int pc = (ks * 4 + quad) ^ (lr & 7);
        bfv[j] = *(const short8*)&Bs[r * 64 + pc * 8];
      }
#pragma unroll
      for (int i = 0; i < 4; ++i)
#pragma unroll
        for (int j = 0; j < 4; ++j)
          acc[i][j] = __builtin_amdgcn_mfma_f32_16x16x32_bf16(af[i], bfv[j], acc[i][j], 0, 0, 0);
    }
  }

#pragma unroll
  for (int i = 0; i < 4; ++i) {
#pragma unroll
    for (int r = 0; r < 4; ++r) {
      int grow = m0 + wm + i * 16 + quad * 4 + r;
      if (grow < count) {
        int tok = tid_list[e * T_TOK + grow];
        float w = tw_list[e * T_TOK + grow];
        size_t rowoff = (size_t)tok * 1024;
#pragma unroll
        for (int j = 0; j < 4; ++j) {
          unsafeAtomicAdd(&out[rowoff + n0 + wn + j * 16 + lr], acc[i][j][r] * w);
        }
      }
    }
  }
}

extern "C" void kernel_launch(void* const* d_in, const int* in_sizes, int n_in,
                              void* d_out, int out_size, void* d_ws, size_t ws_size,
                              hipStream_t stream) {
  const float* x   = (const float*)d_in[0];
  const float* rw1 = (const float*)d_in[1];
  const float* rw2 = (const float*)d_in[2];
  const float* W1  = (const float*)d_in[3];
  const float* W2  = (const float*)d_in[4];
  float* out = (float*)d_out;

  char* ws = (char*)d_ws;
  int*            cnt      = (int*)(ws + 0);        // 32 B
  int*            base     = (int*)(ws + 64);       // 32 B
  int*            fix_cnt  = (int*)(ws + 128);      // 4 B
  int*            tid_list = (int*)(ws + 512);      // 256 KB
  float*          tw_list  = (float*)(ws + 262656); // 256 KB
  unsigned short* xb       = (unsigned short*)(ws + 524800);    // 16 MB
  unsigned short* w1t      = (unsigned short*)(ws + 17302016);  // 32 MB
  unsigned short* w2t      = (unsigned short*)(ws + 50856448);  // 32 MB
  unsigned short* hbuf     = (unsigned short*)(ws + 84410880);  // 64 MB
  int*            tok_top  = (int*)(ws + 151519744);   // 64 KB
  float*          tok_w    = (float*)(ws + 151585280); // 64 KB
  int*            fix_list = (int*)(ws + 151650816);   // 32 KB

  hipMemsetAsync(d_out, 0, (size_t)T_TOK * 1024 * 4, stream);
  hipMemsetAsync(ws, 0, 192, stream);  // cnt, base, fix_cnt

  hipLaunchKernelGGL(router_fp32_kernel, dim3(1024), dim3(256), 0, stream,
                     x, rw1, rw2, tok_top, tok_w, fix_list, fix_cnt);
  hipLaunchKernelGGL(router_fix_kernel, dim3(128), dim3(256), 0, stream,
                     x, rw1, rw2, fix_list, fix_cnt, tok_top, tok_w);
  hipLaunchKernelGGL(scatter_kernel, dim3(32), dim3(256), 0, stream,
                     tok_top, tok_w, cnt, tid_list, tw_list);
  hipLaunchKernelGGL(prefix_kernel, dim3(1), dim3(1), 0, stream, cnt, base);
  hipLaunchKernelGGL(convert_x_kernel, dim3(8192), dim3(256), 0, stream, x, xb);
  hipLaunchKernelGGL(transpose_bf16_kernel, dim3(32, 16, 8), dim3(256), 0, stream,
                     W1, w1t, 1024, 2048);
  hipLaunchKernelGGL(transpose_bf16_kernel, dim3(16, 32, 8), dim3(256), 0, stream,
                     W2, w2t, 2048, 1024);
  hipLaunchKernelGGL(gemm1_kernel, dim3(16, 64, 8), dim3(256), 0, stream,
                     xb, w1t, cnt, base, tid_list, hbuf);
  hipLaunchKernelGGL(gemm2_kernel, dim3(8, 64, 8), dim3(256), 0, stream,
                     hbuf, w2t, cnt, base, tid_list, tw_list, out);
}

// Round 3
// 552.507 us; speedup vs baseline: 1.3779x; 1.0235x over previous
//
#include <hip/hip_runtime.h>
#include <hip/hip_bf16.h>
#include <math.h>

#define T_TOK 8192
#define E_NUM 8
#define GAP_TAU 2e-3f

typedef __attribute__((ext_vector_type(8))) short short8;
typedef __attribute__((ext_vector_type(4))) float floatx4;

__device__ __forceinline__ unsigned short f2bf(float f) {
  unsigned int u = __builtin_bit_cast(unsigned int, f);
  u += 0x7fffu + ((u >> 16) & 1u);
  return (unsigned short)(u >> 16);
}

// async global->LDS, 16B per lane; LDS dest = wave-uniform base + lane*16
__device__ __forceinline__ void async16(const unsigned short* g, unsigned short* l) {
  __builtin_amdgcn_global_load_lds(
      (const __attribute__((address_space(1))) void*)g,
      (__attribute__((address_space(3))) void*)l, 16, 0, 0);
}

// XCD-aware balanced tile map: xcd = flat&7 (hw round-robin heuristic), each
// XCD gets a contiguous band of ACTIVE m-tiles (from cnt[]), n sweeps fastest
// so consecutive blocks on one XCD share the A-tile in its private L2.
__device__ __forceinline__ bool tile_map(int flat, const int* cnt, int nt_log2,
                                         int& e, int& m0, int& n0) {
  const int xcd = flat & 7;
  const int idx = flat >> 3;
  int mtp[E_NUM + 1];
  mtp[0] = 0;
#pragma unroll
  for (int q = 0; q < E_NUM; ++q) mtp[q + 1] = mtp[q] + ((cnt[q] + 127) >> 7);
  const int MT = mtp[E_NUM];
  const int band = (MT + 7) >> 3;
  const int i = idx >> nt_log2;
  if (i >= band) return false;
  const int g = xcd * band + i;
  if (g >= MT) return false;
  e = 0;
#pragma unroll
  for (int q = 0; q < E_NUM - 1; ++q) if (g >= mtp[q + 1]) e = q + 1;
  m0 = (g - mtp[e]) << 7;
  n0 = (idx & ((1 << nt_log2) - 1)) << 7;
  return true;
}

// ---------------- Router pass 1: fp32 logits, top-2, flag small-gap tokens ----
// Also emits xb (bf16 copy of x) as a fused side-product.
__global__ __launch_bounds__(256) void router_fp32_kernel(
    const float* __restrict__ x, const float* __restrict__ rw1,
    const float* __restrict__ rw2,
    int* __restrict__ tok_top, float* __restrict__ tok_w,
    int* __restrict__ fix_list, int* __restrict__ fix_cnt,
    unsigned short* __restrict__ xb) {
  __shared__ __align__(16) float xs[8][1024];  // 32 KB
  __shared__ float ph[128][8];                 // 4 KB
  __shared__ float hs[8][129];
  __shared__ float ls[8][8];
  const int t = threadIdx.x;
  const int tok0 = blockIdx.x * 8;

  {
    const float4* xsrc = (const float4*)(x + (size_t)tok0 * 1024);
    float4* xd = (float4*)&xs[0][0];
    ushort4* xbd = (ushort4*)(xb + (size_t)tok0 * 1024);
#pragma unroll
    for (int i = 0; i < 8; ++i) {
      float4 v = xsrc[t + i * 256];
      xd[t + i * 256] = v;
      ushort4 o;
      o.x = f2bf(v.x); o.y = f2bf(v.y); o.z = f2bf(v.z); o.w = f2bf(v.w);
      xbd[t + i * 256] = o;
    }
  }
  __syncthreads();

  const int j = t & 127, h = t >> 7;
  float acc[8];
#pragma unroll
  for (int tt = 0; tt < 8; ++tt) acc[tt] = 0.f;

  const int dbeg = h * 512, dend = dbeg + 512;
#pragma unroll 2
  for (int d0 = dbeg; d0 < dend; d0 += 4) {
    float w0 = rw1[(d0 + 0) * 128 + j];
    float w1 = rw1[(d0 + 1) * 128 + j];
    float w2 = rw1[(d0 + 2) * 128 + j];
    float w3 = rw1[(d0 + 3) * 128 + j];
    float4 xv[8];
#pragma unroll
    for (int tt = 0; tt < 8; ++tt) xv[tt] = *(const float4*)&xs[tt][d0];
#pragma unroll
    for (int tt = 0; tt < 8; ++tt) {
      acc[tt] = fmaf(xv[tt].x, w0, acc[tt]);
      acc[tt] = fmaf(xv[tt].y, w1, acc[tt]);
      acc[tt] = fmaf(xv[tt].z, w2, acc[tt]);
      acc[tt] = fmaf(xv[tt].w, w3, acc[tt]);
    }
  }
  if (h == 1) {
#pragma unroll
    for (int tt = 0; tt < 8; ++tt) ph[j][tt] = acc[tt];
  }
  __syncthreads();
  if (h == 0) {
#pragma unroll
    for (int tt = 0; tt < 8; ++tt) {
      float a = acc[tt] + ph[j][tt];
      hs[tt][j] = a / (1.f + expf(-a));
    }
  }
  __syncthreads();
  if (t < 64) {
    int tt = t >> 3, e = t & 7;
    float l = 0.f;
#pragma unroll 4
    for (int jj = 0; jj < 128; ++jj) l = fmaf(hs[tt][jj], rw2[jj * 8 + e], l);
    ls[tt][e] = l;
  }
  __syncthreads();
  if (t < 8) {
    int tt = t;
    float l[8];
#pragma unroll
    for (int e = 0; e < 8; ++e) l[e] = ls[tt][e];
    int i0 = 0;
#pragma unroll
    for (int e = 1; e < 8; ++e) if (l[e] > l[i0]) i0 = e;
    int i1 = (i0 == 0) ? 1 : 0;
#pragma unroll
    for (int e = 0; e < 8; ++e) if (e != i0 && l[e] > l[i1]) i1 = e;
    float v2 = -3.4e38f;
#pragma unroll
    for (int e = 0; e < 8; ++e) if (e != i0 && e != i1 && l[e] > v2) v2 = l[e];
    float gap = l[i1] - v2;
    float p = expf(l[i1] - l[i0]);
    float w0 = 1.f / (1.f + p);
    int tok = tok0 + tt;
    tok_top[2 * tok] = i0; tok_top[2 * tok + 1] = i1;
    tok_w[2 * tok] = w0;   tok_w[2 * tok + 1] = 1.f - w0;
    if (gap < GAP_TAU) { int pos = atomicAdd(fix_cnt, 1); fix_list[pos] = tok; }
  }
}

// ---------------- Router pass 2: exact fp64 recompute for flagged tokens ----
__global__ __launch_bounds__(256) void router_fix_kernel(
    const float* __restrict__ x, const float* __restrict__ rw1,
    const float* __restrict__ rw2, const int* __restrict__ fix_list,
    const int* __restrict__ fix_cnt,
    int* __restrict__ tok_top, float* __restrict__ tok_w) {
  __shared__ __align__(16) float xs[1024];
  __shared__ double red[128];
  __shared__ double hs[128];
  __shared__ double ls[8];
  const int t = threadIdx.x;
  const int nfix = *fix_cnt;
  for (int it = blockIdx.x; it < nfix; it += gridDim.x) {
    int tok = fix_list[it];
    ((float4*)xs)[t] = ((const float4*)(x + (size_t)tok * 1024))[t];
    __syncthreads();
    const int j = t & 127, h = t >> 7;
    double a0 = 0, a1 = 0, a2 = 0, a3 = 0;
    const int dbeg = h * 512;
    for (int d0 = dbeg; d0 < dbeg + 512; d0 += 4) {
      a0 = fma((double)xs[d0 + 0], (double)rw1[(d0 + 0) * 128 + j], a0);
      a1 = fma((double)xs[d0 + 1], (double)rw1[(d0 + 1) * 128 + j], a1);
      a2 = fma((double)xs[d0 + 2], (double)rw1[(d0 + 2) * 128 + j], a2);
      a3 = fma((double)xs[d0 + 3], (double)rw1[(d0 + 3) * 128 + j], a3);
    }
    double a = (a0 + a1) + (a2 + a3);
    if (h == 1) red[j] = a;
    __syncthreads();
    if (h == 0) {
      double s = a + red[j];
      hs[j] = s / (1.0 + exp(-s));
    }
    __syncthreads();
    if (t < 8) {
      int e = t;
      double l = 0;
      for (int jj = 0; jj < 128; ++jj) l = fma(hs[jj], (double)rw2[jj * 8 + e], l);
      ls[e] = l;
    }
    __syncthreads();
    if (t == 0) {
      double l[8];
#pragma unroll
      for (int e = 0; e < 8; ++e) l[e] = ls[e];
      int i0 = 0;
#pragma unroll
      for (int e = 1; e < 8; ++e) if (l[e] > l[i0]) i0 = e;
      int i1 = (i0 == 0) ? 1 : 0;
#pragma unroll
      for (int e = 0; e < 8; ++e) if (e != i0 && l[e] > l[i1]) i1 = e;
      double p = exp(l[i1] - l[i0]);
      double w0 = 1.0 / (1.0 + p);
      tok_top[2 * tok] = i0; tok_top[2 * tok + 1] = i1;
      tok_w[2 * tok] = (float)w0; tok_w[2 * tok + 1] = (float)(1.0 - w0);
    }
    __syncthreads();
  }
}

// ---------------- Scatter: build per-expert token lists (block-aggregated) ----
__global__ __launch_bounds__(256) void scatter_kernel(
    const int* __restrict__ tok_top, const float* __restrict__ tok_w,
    int* __restrict__ cnt, int* __restrict__ tid_list, float* __restrict__ tw_list) {
  __shared__ int hist[8], run[8];
  const int t = threadIdx.x;
  if (t < 8) hist[t] = 0;
  __syncthreads();
  const int tok = blockIdx.x * 256 + t;
  const int e0 = tok_top[2 * tok], e1 = tok_top[2 * tok + 1];
  atomicAdd(&hist[e0], 1);
  atomicAdd(&hist[e1], 1);
  __syncthreads();
  if (t < 8) run[t] = atomicAdd(&cnt[t], hist[t]);
  __syncthreads();
  int p0 = atomicAdd(&run[e0], 1);
  tid_list[e0 * T_TOK + p0] = tok; tw_list[e0 * T_TOK + p0] = tok_w[2 * tok];
  int p1 = atomicAdd(&run[e1], 1);
  tid_list[e1 * T_TOK + p1] = tok; tw_list[e1 * T_TOK + p1] = tok_w[2 * tok + 1];
}

__global__ void prefix_kernel(const int* __restrict__ cnt, int* __restrict__ base) {
  if (threadIdx.x == 0 && blockIdx.x == 0) {
    int s = 0;
    for (int e = 0; e < E_NUM; ++e) { base[e] = s; s += cnt[e]; }
  }
}

// ---------------- tiled transpose + convert: [e][R][C] fp32 -> [e][C][R] bf16 ----
__global__ __launch_bounds__(256) void transpose_bf16_kernel(
    const float* __restrict__ in, unsigned short* __restrict__ out, int R, int C) {
  __shared__ unsigned short tile[64][65];
  const int e = blockIdx.z;
  const int r0 = blockIdx.y * 64, c0 = blockIdx.x * 64;
  const float* src = in + (size_t)e * R * C;
  unsigned short* dst = out + (size_t)e * R * C;
  const int t = threadIdx.x;
  const int cc = (t & 15) * 4;
#pragma unroll
  for (int p = 0; p < 4; ++p) {
    int r = p * 16 + (t >> 4);
    float4 v = *(const float4*)(src + (size_t)(r0 + r) * C + c0 + cc);
    tile[cc + 0][r] = f2bf(v.x);
    tile[cc + 1][r] = f2bf(v.y);
    tile[cc + 2][r] = f2bf(v.z);
    tile[cc + 3][r] = f2bf(v.w);
  }
  __syncthreads();
#pragma unroll
  for (int p = 0; p < 4; ++p) {
    int fr = p * 16 + (t >> 4);
    ushort4 o;
    o.x = tile[fr][cc + 0]; o.y = tile[fr][cc + 1];
    o.z = tile[fr][cc + 2]; o.w = tile[fr][cc + 3];
    *(ushort4*)(dst + (size_t)(c0 + fr) * R + r0 + cc) = o;
  }
}

// ============ GEMM1: h[slot][f] = silu( x[tok][:] @ W1t[e][f][:] ) =============
__global__ __launch_bounds__(256) void gemm1_kernel(
    const unsigned short* __restrict__ xb,   // [T][1024] bf16
    const unsigned short* __restrict__ w1t,  // [E][2048][1024] bf16
    const int* __restrict__ cnt, const int* __restrict__ base,
    const int* __restrict__ tid_list,
    unsigned short* __restrict__ h_buf) {    // [2T][2048] bf16
  int e, m0, n0;
  if (!tile_map(blockIdx.x, cnt, 4, e, m0, n0)) return;  // NT=16
  const int count = cnt[e];
  const int bs = base[e];

  __shared__ __align__(16) unsigned short As[128 * 64];
  __shared__ __align__(16) unsigned short Bs[128 * 64];

  const int t = threadIdx.x;
  const int wv = t >> 6, lane = t & 63;
  const int quad = lane >> 4, lr = lane & 15;
  const int wm = (wv & 1) * 64, wn = (wv >> 1) * 64;
  const int lr8 = lane >> 3, lc8 = lane & 7;
  const int chunk = lc8 ^ lr8;

  const unsigned short* aptr[4];
  const unsigned short* bptr[4];
#pragma unroll
  for (int q = 0; q < 4; ++q) {
    int ar = m0 + wv * 32 + q * 8 + lr8;
    int ai = ar < count ? ar : count - 1;
    int tok = tid_list[e * T_TOK + ai];
    aptr[q] = xb + (size_t)tok * 1024 + chunk * 8;
    int br = n0 + wv * 32 + q * 8 + lr8;
    bptr[q] = w1t + ((size_t)e * 2048 + br) * 1024 + chunk * 8;
  }
  unsigned short* aldsb = &As[wv * 2048];
  unsigned short* bldsb = &Bs[wv * 2048];

  floatx4 zero = {0.f, 0.f, 0.f, 0.f};
  floatx4 acc[4][4];
#pragma unroll
  for (int i = 0; i < 4; ++i)
#pragma unroll
    for (int j = 0; j < 4; ++j) acc[i][j] = zero;

  for (int k0 = 0; k0 < 1024; k0 += 64) {
    __syncthreads();
#pragma unroll
    for (int q = 0; q < 4; ++q) {
      async16(aptr[q] + k0, aldsb + q * 512);
      async16(bptr[q] + k0, bldsb + q * 512);
    }
    __syncthreads();
#pragma unroll
    for (int ks = 0; ks < 2; ++ks) {
      short8 af[4], bfv[4];
#pragma unroll
      for (int i = 0; i < 4; ++i) {
        int r = wm + i * 16 + lr;
        int pc = (ks * 4 + quad) ^ (lr & 7);
        af[i] = *(const short8*)&As[r * 64 + pc * 8];
      }
#pragma unroll
      for (int j = 0; j < 4; ++j) {
        int r = wn + j * 16 + lr;
        int pc = (ks * 4 + quad) ^ (lr & 7);
        bfv[j] = *(const short8*)&Bs[r * 64 + pc * 8];
      }
#pragma unroll
      for (int i = 0; i < 4; ++i)
#pragma unroll
        for (int j = 0; j < 4; ++j)
          acc[i][j] = __builtin_amdgcn_mfma_f32_16x16x32_bf16(af[i], bfv[j], acc[i][j], 0, 0, 0);
    }
  }

#pragma unroll
  for (int i = 0; i < 4; ++i) {
#pragma unroll
    for (int r = 0; r < 4; ++r) {
      int grow = m0 + wm + i * 16 + quad * 4 + r;
      if (grow < count) {
        size_t rowoff = (size_t)(bs + grow) * 2048;
#pragma unroll
        for (int j = 0; j < 4; ++j) {
          float v = acc[i][j][r];
          float s = v / (1.0f + __expf(-v));
          h_buf[rowoff + n0 + wn + j * 16 + lr] = f2bf(s);
        }
      }
    }
  }
}

// ============ GEMM2: out[tok][:] += w * ( h[slot][:] @ W2t[e][d][:] ) ==========
__global__ __launch_bounds__(256) void gemm2_kernel(
    const unsigned short* __restrict__ h_buf,  // [2T][2048] bf16
    const unsigned short* __restrict__ w2t,    // [E][1024][2048] bf16
    const int* __restrict__ cnt, const int* __restrict__ base,
    const int* __restrict__ tid_list, const float* __restrict__ tw_list,
    float* __restrict__ out) {                 // [T][1024] fp32
  int e, m0, n0;
  if (!tile_map(blockIdx.x, cnt, 3, e, m0, n0)) return;  // NT=8
  const int count = cnt[e];
  const int bs = base[e];

  __shared__ __align__(16) unsigned short As[128 * 64];
  __shared__ __align__(16) unsigned short Bs[128 * 64];

  const int t = threadIdx.x;
  const int wv = t >> 6, lane = t & 63;
  const int quad = lane >> 4, lr = lane & 15;
  const int wm = (wv & 1) * 64, wn = (wv >> 1) * 64;
  const int lr8 = lane >> 3, lc8 = lane & 7;
  const int chunk = lc8 ^ lr8;

  const unsigned short* aptr[4];
  const unsigned short* bptr[4];
#pragma unroll
  for (int q = 0; q < 4; ++q) {
    int ar = m0 + wv * 32 + q * 8 + lr8;
    int ai = ar < count ? ar : count - 1;
    aptr[q] = h_buf + (size_t)(bs + ai) * 2048 + chunk * 8;
    int br = n0 + wv * 32 + q * 8 + lr8;
    bptr[q] = w2t + ((size_t)e * 1024 + br) * 2048 + chunk * 8;
  }
  unsigned short* aldsb = &As[wv * 2048];
  unsigned short* bldsb = &Bs[wv * 2048];

  floatx4 zero = {0.f, 0.f, 0.f, 0.f};
  floatx4 acc[4][4];
#pragma unroll
  for (int i = 0; i < 4; ++i)
#pragma unroll
    for (int j = 0; j < 4; ++j) acc[i][j] = zero;

  for (int k0 = 0; k0 < 2048; k0 += 64) {
    __syncthreads();
#pragma unroll
    for (int q = 0; q < 4; ++q) {
      async16(aptr[q] + k0, aldsb + q * 512);
      async16(bptr[q] + k0, bldsb + q * 512);
    }
    __syncthreads();
#pragma unroll
    for (int ks = 0; ks < 2; ++ks) {
      short8 af[4], bfv[4];
#pragma unroll
      for (int i = 0; i < 4; ++i) {
        int r = wm + i * 16 + lr;
        int pc = (ks * 4 + quad) ^ (lr & 7);
        af[i] = *(const short8*)&As[r * 64 + pc * 8];
      }
#pragma unroll
      for (int j = 0; j < 4; ++j) {
        int r = wn + j * 16 + lr;
        int pc = (ks * 4 + quad) ^ (lr & 7);
        bfv[j] = *(const short8*)&Bs[r * 64 + pc * 8];
      }
#pragma unroll
      for (int i = 0; i < 4; ++i)
#pragma unroll
        for (int j = 0; j < 4; ++j)
          acc[i][j] = __builtin_amdgcn_mfma_f32_16x16x32_bf16(af[i], bfv[j], acc[i][j], 0, 0, 0);
    }
  }

#pragma unroll
  for (int i = 0; i < 4; ++i) {
#pragma unroll
    for (int r = 0; r < 4; ++r) {
      int grow = m0 + wm + i * 16 + quad * 4 + r;
      if (grow < count) {
        int tok = tid_list[e * T_TOK + grow];
        float w = tw_list[e * T_TOK + grow];
        size_t rowoff = (size_t)tok * 1024;
#pragma unroll
        for (int j = 0; j < 4; ++j) {
          unsafeAtomicAdd(&out[rowoff + n0 + wn + j * 16 + lr], acc[i][j][r] * w);
        }
      }
    }
  }
}

extern "C" void kernel_launch(void* const* d_in, const int* in_sizes, int n_in,
                              void* d_out, int out_size, void* d_ws, size_t ws_size,
                              hipStream_t stream) {
  const float* x   = (const float*)d_in[0];
  const float* rw1 = (const float*)d_in[1];
  const float* rw2 = (const float*)d_in[2];
  const float* W1  = (const float*)d_in[3];
  const float* W2  = (const float*)d_in[4];
  float* out = (float*)d_out;

  char* ws = (char*)d_ws;
  int*            cnt      = (int*)(ws + 0);        // 32 B
  int*            base     = (int*)(ws + 64);       // 32 B
  int*            fix_cnt  = (int*)(ws + 128);      // 4 B
  int*            tid_list = (int*)(ws + 512);      // 256 KB
  float*          tw_list  = (float*)(ws + 262656); // 256 KB
  unsigned short* xb       = (unsigned short*)(ws + 524800);    // 16 MB
  unsigned short* w1t      = (unsigned short*)(ws + 17302016);  // 32 MB
  unsigned short* w2t      = (unsigned short*)(ws + 50856448);  // 32 MB
  unsigned short* hbuf     = (unsigned short*)(ws + 84410880);  // 64 MB
  int*            tok_top  = (int*)(ws + 151519744);   // 64 KB
  float*          tok_w    = (float*)(ws + 151585280); // 64 KB
  int*            fix_list = (int*)(ws + 151650816);   // 32 KB

  hipMemsetAsync(d_out, 0, (size_t)T_TOK * 1024 * 4, stream);
  hipMemsetAsync(ws, 0, 192, stream);  // cnt, base, fix_cnt

  hipLaunchKernelGGL(router_fp32_kernel, dim3(1024), dim3(256), 0, stream,
                     x, rw1, rw2, tok_top, tok_w, fix_list, fix_cnt, xb);
  hipLaunchKernelGGL(router_fix_kernel, dim3(128), dim3(256), 0, stream,
                     x, rw1, rw2, fix_list, fix_cnt, tok_top, tok_w);
  hipLaunchKernelGGL(scatter_kernel, dim3(32), dim3(256), 0, stream,
                     tok_top, tok_w, cnt, tid_list, tw_list);
  hipLaunchKernelGGL(prefix_kernel, dim3(1), dim3(1), 0, stream, cnt, base);
  hipLaunchKernelGGL(transpose_bf16_kernel, dim3(32, 16, 8), dim3(256), 0, stream,
                     W1, w1t, 1024, 2048);
  hipLaunchKernelGGL(transpose_bf16_kernel, dim3(16, 32, 8), dim3(256), 0, stream,
                     W2, w2t, 2048, 1024);
  // grids: 8 XCDs * band(<=17) * NT  ->  8*17*16 = 2176 , 8*17*8 = 1088
  hipLaunchKernelGGL(gemm1_kernel, dim3(2176), dim3(256), 0, stream,
                     xb, w1t, cnt, base, tid_list, hbuf);
  hipLaunchKernelGGL(gemm2_kernel, dim3(1088), dim3(256), 0, stream,
                     hbuf, w2t, cnt, base, tid_list, tw_list, out);
}